// Round 12
// baseline (571.900 us; speedup 1.0000x reference)
//
#include <hip/hip_runtime.h>
#include <math.h>

// ---------------------------------------------------------------------------
// EfficientAttention (dual-stream) — round 12: wide-tile pw GEMM.
//   pw_mfma: wave tile 64m x 128s (4A+8B reads -> 32 MFMA per kf, 2.67/read),
//   block 128m x 256s. A dbuf via global_load_lds (DMA t+1 before MFMA t);
//   B single buffer, reg-prefetch + swizzled scatter after barrier.
//   2-pass epilogues per s-half. rp: f32 epilogue, bijective XCD swizzle(784).
//   dwv, ctx/att MFMA, LN fusion identical to round 11.
// ---------------------------------------------------------------------------

constexpr int NN = 4;
constexpr int C1 = 256;
constexpr int C2 = 512;
constexpr int TT = 16;
constexpr int SP = TT * 28 * 28;                  // 12544
constexpr long long NB = (long long)NN * C2 * SP; // 25,690,112
constexpr int HEADS = 8;
constexpr int CTX_CHUNKS = 7;
constexpr int SBLKS = 49;                         // s-blocks of 256
constexpr int STATS_PARTS = SBLKS * 4 * 4;        // rp grid = 784
constexpr double TOTAL_ELEMS = (double)NB;

typedef __attribute__((ext_vector_type(8))) short bf16x8;
typedef __attribute__((ext_vector_type(4))) short bf16x4;
typedef __attribute__((ext_vector_type(4))) float f32x4;

__device__ __forceinline__ short f2bf(float f)
{
    unsigned u = __float_as_uint(f);
    unsigned r = u + 0x7FFFu + ((u >> 16) & 1u);
    return (short)(r >> 16);
}
__device__ __forceinline__ float bf2f(short s)
{
    return __uint_as_float(((unsigned)(unsigned short)s) << 16);
}

__device__ __forceinline__ float4 loadvec4(const float* p)
{
    return *(const float4*)p;
}
__device__ __forceinline__ float4 loadvec4(const short* p)
{
    bf16x4 v = *(const bf16x4*)p;
    return (float4){bf2f(v[0]), bf2f(v[1]), bf2f(v[2]), bf2f(v[3])};
}

__device__ __forceinline__ void gload16(const short* g, short* l)
{
    __builtin_amdgcn_global_load_lds(
        (const __attribute__((address_space(1))) unsigned int*)g,
        (__attribute__((address_space(3))) unsigned int*)l,
        16, 0, 0);
}

// ---------------- merged fp32 -> bf16 weight conversion --------------------
__global__ __launch_bounds__(256)
void wcvt_kernel(const float* __restrict__ w0, const float* __restrict__ w1,
                 const float* __restrict__ w2, const float* __restrict__ w3,
                 const float* __restrict__ w4, const float* __restrict__ w5,
                 const float* __restrict__ w6, short* __restrict__ out)
{
    int i = blockIdx.x * 256 + threadIdx.x;
    if (i >= 655360) return;
    const float* src; int off;
    if (i < 393216) {
        int seg = i >> 16; off = i & 65535;
        src = seg == 0 ? w0 : seg == 1 ? w1 : seg == 2 ? w2
            : seg == 3 ? w3 : seg == 4 ? w4 : w5;
    } else { src = w6; off = i - 393216; }
    out[i] = f2bf(src[off]);
}

// ---------------- depthwise 3x3x3 (prefetched, vectorized) -----------------
template<typename IT, int NSET>
__global__ __launch_bounds__(256)
void dwv_kernel(const IT* __restrict__ in,
                const float* __restrict__ w0c, const float* __restrict__ b0c,
                short* __restrict__ o0,
                const float* __restrict__ w1c, const float* __restrict__ b1c,
                short* __restrict__ o1,
                const float* __restrict__ w2c, const float* __restrict__ b2c,
                short* __restrict__ o2, int Cin)
{
    const int split = blockIdx.x, c = blockIdx.y, n = blockIdx.z;
    const int t0 = split * 8, t1 = t0 + 8;
    const int zs = (t0 - 1 > 0) ? t0 - 1 : 0;
    const int ze = (t1 < 15) ? t1 : 15;
    __shared__ float tile[2][900];
    const int tid = threadIdx.x;
    const size_t ibase = ((size_t)(n * Cin + c)) * TT * 784;
    const IT* inp = in + ibase;

    const float* wp[3] = {w0c, w1c, w2c};
    const float* bp[3] = {b0c, b1c, b2c};
    short* op[3] = {o0, o1, o2};
    float w[NSET][27], bv[NSET];
#pragma unroll
    for (int g = 0; g < NSET; ++g) {
#pragma unroll
        for (int i = 0; i < 27; ++i) w[g][i] = wp[g][c * 27 + i];
        bv[g] = bp[g][c];
    }

    for (int i = tid; i < 1800; i += 256) ((float*)tile)[i] = 0.f;

    const bool act = tid < 196;
    const int pos = tid * 4;
    const int hh = pos / 28, ww = pos - hh * 28;
    const int ladr = (hh + 1) * 30 + ww + 1;
    const int rbase = hh * 30 + ww;

    float4 preg = {0.f, 0.f, 0.f, 0.f};
    if (act) preg = loadvec4(inp + (size_t)zs * 784 + pos);

    float a0[NSET][4], a1[NSET][4], a2[NSET][4];
#pragma unroll
    for (int g = 0; g < NSET; ++g)
#pragma unroll
        for (int k = 0; k < 4; ++k) { a0[g][k] = bv[g]; a1[g][k] = bv[g]; a2[g][k] = bv[g]; }

    for (int z = zs; z <= ze; ++z) {
        float* tb = tile[z & 1];
        __syncthreads();
        if (act) {
            tb[ladr] = preg.x; tb[ladr + 1] = preg.y;
            tb[ladr + 2] = preg.z; tb[ladr + 3] = preg.w;
            if (z < ze) preg = loadvec4(inp + (size_t)(z + 1) * 784 + pos);
        }
        __syncthreads();
        if (act) {
            float v[3][6];
#pragma unroll
            for (int r = 0; r < 3; ++r)
#pragma unroll
                for (int j = 0; j < 6; ++j)
                    v[r][j] = tb[rbase + r * 30 + j];
#pragma unroll
            for (int g = 0; g < NSET; ++g)
#pragma unroll
                for (int dh = 0; dh < 3; ++dh)
#pragma unroll
                    for (int dw = 0; dw < 3; ++dw) {
                        const float wa = w[g][18 + dh * 3 + dw];
                        const float wb = w[g][9 + dh * 3 + dw];
                        const float wc2 = w[g][dh * 3 + dw];
#pragma unroll
                        for (int k = 0; k < 4; ++k) {
                            const float val = v[dh][k + dw];
                            a0[g][k] += val * wa;
                            a1[g][k] += val * wb;
                            a2[g][k] += val * wc2;
                        }
                    }
            if (z - 1 >= t0) {
#pragma unroll
                for (int g = 0; g < NSET; ++g) {
                    bf16x4 pk;
#pragma unroll
                    for (int k = 0; k < 4; ++k) pk[k] = f2bf(a0[g][k]);
                    *(bf16x4*)&op[g][ibase + (size_t)(z - 1) * 784 + pos] = pk;
                }
            }
#pragma unroll
            for (int g = 0; g < NSET; ++g)
#pragma unroll
                for (int k = 0; k < 4; ++k) {
                    a0[g][k] = a1[g][k]; a1[g][k] = a2[g][k]; a2[g][k] = bv[g];
                }
        }
    }
    if (act && ze >= t0 && ze < t1) {
#pragma unroll
        for (int g = 0; g < NSET; ++g) {
            bf16x4 pk;
#pragma unroll
            for (int k = 0; k < 4; ++k) pk[k] = f2bf(a0[g][k]);
            *(bf16x4*)&op[g][ibase + (size_t)ze * 784 + pos] = pk;
        }
    }
}

// ---------------- pointwise conv: wide-tile bf16 MFMA GEMM -----------------
// Block tile 128m x 256s; wave tile 64m x 128s (wr = m-half, wc = s-half).
// A: [128][64] dbuf via global_load_lds (slot = kb ^ (row&7)).
// B: [256][72] single buf; reg-prefetch + scatter; slot = kb ^ ((srow>>4)&7).
// MODE 0: batched K(seg0)+V(seg1) -> bf16 [n][c][s]; K emits row (max,expsum).
// MODE 1: Q -> bf16 [n][s][512].
// MODE 2: rp -> x bf16 [n][c][s] + LN partials; XCD-swizzled 1D grid (784).
template<int MODE>
__global__ __launch_bounds__(256)
void pw_mfma_kernel(const short* __restrict__ WbA, const float* __restrict__ biasA,
                    const short* __restrict__ actA, short* __restrict__ outA,
                    const short* __restrict__ WbV, const float* __restrict__ biasV,
                    const short* __restrict__ actV, short* __restrict__ outV,
                    const float* __restrict__ rgb, const float* __restrict__ flow,
                    double* __restrict__ partials, float2* __restrict__ kpart,
                    int Cin, size_t nStride, size_t cStride, int chOff)
{
    __shared__ short smem[34816];     // A dbuf 2x8192 | Bs 18432 (69.6 KB)
    short* Bs = smem + 16384;
    const int tid = threadIdx.x;
    const int w = tid >> 6, lane = tid & 63;
    int s0, m0, n, seg = 0, sBlk;
    if constexpr (MODE == 2) {
        const int bid = blockIdx.x;                   // 784 blocks
        const int wgid = (bid & 7) * 98 + (bid >> 3); // bijective chunked
        const int panel = wgid >> 2, mBlk = wgid & 3;
        n = panel / SBLKS; sBlk = panel % SBLKS;
        s0 = sBlk * 256; m0 = mBlk * 128;
    } else {
        sBlk = blockIdx.x; s0 = sBlk * 256; n = blockIdx.z;
        if constexpr (MODE == 0) { seg = blockIdx.y >> 1; m0 = (blockIdx.y & 1) * 128; }
        else m0 = blockIdx.y * 128;
    }
    const short* Wb = (MODE == 0 && seg) ? WbV : WbA;
    const float* bias = (MODE == 0 && seg) ? biasV : biasA;
    const short* actp = (MODE == 0 && seg) ? actV : actA;
    short* outB = (MODE == 0 && seg) ? outV : outA;

    const short* aSrc = Wb + (size_t)m0 * Cin;
    const short* bSrc = actp + (size_t)n * Cin * SP;
    f32x4 acc[4][8];
#pragma unroll
    for (int i = 0; i < 4; ++i)
#pragma unroll
        for (int j = 0; j < 8; ++j)
            acc[i][j] = (f32x4){0.f, 0.f, 0.f, 0.f};
    const int lrow = lane >> 3, lslot = lane & 7;
    const int wr = w >> 1, wc = w & 1;
    const int kg = tid >> 4, scb = tid & 15;   // B stage: 4 k-rows x 16 s
    const int nt = Cin >> 6;

    bf16x8 breg[8];
    // ---- prologue: A-DMA(0)->buf0, B(0) load + scatter ----
#pragma unroll
    for (int cc = 0; cc < 4; ++cc) {
        const int chunk = w * 4 + cc;
        const int row = chunk * 8 + lrow;
        const int ss = lslot ^ (row & 7);
        gload16(aSrc + (size_t)row * Cin + ss * 8, &smem[chunk * 512]);
    }
#pragma unroll
    for (int r = 0; r < 4; ++r)
#pragma unroll
        for (int h = 0; h < 2; ++h)
            breg[r * 2 + h] = *(const bf16x8*)(bSrc + (size_t)(kg * 4 + r) * SP
                                               + s0 + scb * 16 + h * 8);
#pragma unroll
    for (int h = 0; h < 2; ++h)
#pragma unroll
        for (int j = 0; j < 8; ++j) {
            bf16x4 pk;
#pragma unroll
            for (int r = 0; r < 4; ++r) pk[r] = breg[r * 2 + h][j];
            const int srow = scb * 16 + h * 8 + j;
            const int slot = (kg >> 1) ^ (scb & 7);
            *(bf16x4*)&Bs[srow * 72 + slot * 8 + (kg & 1) * 4] = pk;
        }
    __syncthreads();

    for (int t = 0; t < nt; ++t) {
        const bool more = (t + 1) < nt;
        if (more) {
            const int kt = (t + 1) << 6;
            const int buf = (t + 1) & 1;
#pragma unroll
            for (int cc = 0; cc < 4; ++cc) {
                const int chunk = w * 4 + cc;
                const int row = chunk * 8 + lrow;
                const int ss = lslot ^ (row & 7);
                gload16(aSrc + (size_t)row * Cin + kt + ss * 8,
                        &smem[buf * 8192 + chunk * 512]);
            }
#pragma unroll
            for (int r = 0; r < 4; ++r)
#pragma unroll
                for (int h = 0; h < 2; ++h)
                    breg[r * 2 + h] = *(const bf16x8*)(bSrc + (size_t)(kt + kg * 4 + r) * SP
                                                       + s0 + scb * 16 + h * 8);
        }
        const short* cA = smem + (t & 1) * 8192;
#pragma unroll
        for (int kf = 0; kf < 2; ++kf) {
            const int kb = kf * 4 + (lane >> 4);
            bf16x8 af[4], bfr[8];
#pragma unroll
            for (int i = 0; i < 4; ++i) {
                const int row = wr * 64 + i * 16 + (lane & 15);
                af[i] = *(const bf16x8*)&cA[row * 64 + ((kb ^ (row & 7)) << 3)];
            }
#pragma unroll
            for (int j = 0; j < 8; ++j) {
                const int srow = wc * 128 + j * 16 + (lane & 15);
                bfr[j] = *(const bf16x8*)&Bs[srow * 72 + ((kb ^ ((srow >> 4) & 7)) << 3)];
            }
#pragma unroll
            for (int i = 0; i < 4; ++i)
#pragma unroll
                for (int j = 0; j < 8; ++j)
                    acc[i][j] = __builtin_amdgcn_mfma_f32_16x16x32_bf16(
                        af[i], bfr[j], acc[i][j], 0, 0, 0);
        }
        __syncthreads();                       // B reads done
        if (more) {
#pragma unroll
            for (int h = 0; h < 2; ++h)
#pragma unroll
                for (int j = 0; j < 8; ++j) {
                    bf16x4 pk;
#pragma unroll
                    for (int r = 0; r < 4; ++r) pk[r] = breg[r * 2 + h][j];
                    const int srow = scb * 16 + h * 8 + j;
                    const int slot = (kg >> 1) ^ (scb & 7);
                    *(bf16x4*)&Bs[srow * 72 + slot * 8 + (kg & 1) * 4] = pk;
                }
        }
        __syncthreads();                       // B(t+1) ready; A-DMA drained
    }

    if constexpr (MODE == 0) {
        short* ep = smem;                      // [128 m][136 s-half]
        float mrun = -1e30f, srun = 0.f;
#pragma unroll
        for (int h = 0; h < 2; ++h) {
            __syncthreads();
            if (wc == h) {
#pragma unroll
                for (int i = 0; i < 4; ++i) {
                    const int mloc = wr * 64 + i * 16 + (lane >> 4) * 4;
#pragma unroll
                    for (int j = 0; j < 8; ++j) {
                        const int sloc = j * 16 + (lane & 15);
#pragma unroll
                        for (int r = 0; r < 4; ++r)
                            ep[(mloc + r) * 136 + sloc] =
                                f2bf(acc[i][j][r] + bias[m0 + mloc + r]);
                    }
                }
            }
            __syncthreads();
            short* op = outB + (size_t)n * nStride;
#pragma unroll
            for (int cc = 0; cc < 8; ++cc) {
                const int idx = tid + cc * 256;
                const int mloc = idx >> 4, ch = idx & 15;
                bf16x8 v = *(const bf16x8*)&ep[mloc * 136 + ch * 8];
                *(bf16x8*)&op[(size_t)(chOff + m0 + mloc) * cStride
                              + s0 + h * 128 + ch * 8] = v;
            }
            if (seg == 0) {
                const int row = tid >> 1, half = tid & 1;
                const short* rp = &ep[row * 136 + half * 64];
                float mx = -1e30f;
#pragma unroll 8
                for (int j = 0; j < 64; ++j) mx = fmaxf(mx, bf2f(rp[j]));
                float sum = 0.f;
#pragma unroll 8
                for (int j = 0; j < 64; ++j) sum += __expf(bf2f(rp[j]) - mx);
                const float mo = __shfl_xor(mx, 1, 64);
                const float so = __shfl_xor(sum, 1, 64);
                const float mg = fmaxf(mx, mo);
                const float sg = sum * __expf(mx - mg) + so * __expf(mo - mg);
                const float nm = fmaxf(mrun, mg);
                srun = srun * __expf(mrun - nm) + sg * __expf(mg - nm);
                mrun = nm;
            }
        }
        if (seg == 0 && (tid & 1) == 0)
            kpart[(size_t)(n * 512 + chOff + m0 + (tid >> 1)) * SBLKS + sBlk] =
                (float2){mrun, srun};
    } else if constexpr (MODE == 1) {
        short* ep = smem;                      // [128 s][136 m]
#pragma unroll
        for (int h = 0; h < 2; ++h) {
            __syncthreads();
            if (wc == h) {
#pragma unroll
                for (int i = 0; i < 4; ++i) {
                    const int mb = wr * 64 + i * 16 + (lane >> 4) * 4;
#pragma unroll
                    for (int j = 0; j < 8; ++j) {
                        const int sloc = j * 16 + (lane & 15);
                        bf16x4 pk;
#pragma unroll
                        for (int r = 0; r < 4; ++r)
                            pk[r] = f2bf(acc[i][j][r] + bias[m0 + mb + r]);
                        *(bf16x4*)&ep[sloc * 136 + mb] = pk;
                    }
                }
            }
            __syncthreads();
#pragma unroll
            for (int cc = 0; cc < 8; ++cc) {
                const int idx = tid + cc * 256;
                const int sloc = idx >> 4, ch = idx & 15;
                bf16x8 v = *(const bf16x8*)&ep[sloc * 136 + ch * 8];
                *(bf16x8*)&outA[((size_t)n * SP + s0 + h * 128 + sloc) * 512
                                + chOff + m0 + ch * 8] = v;
            }
        }
    } else {
        float* ep = (float*)smem;              // [128 m][132 s-half] f32
        short* xo = outA + (size_t)n * C2 * SP;
        const float* rbase = (m0 < 256)
            ? rgb + ((size_t)n * 256 + m0) * SP
            : flow + ((size_t)n * 256 + (m0 - 256)) * SP;
        double ls = 0.0, lss = 0.0;
#pragma unroll
        for (int h = 0; h < 2; ++h) {
            __syncthreads();
            if (wc == h) {
#pragma unroll
                for (int i = 0; i < 4; ++i) {
                    const int mloc = wr * 64 + i * 16 + (lane >> 4) * 4;
#pragma unroll
                    for (int j = 0; j < 8; ++j) {
                        const int sloc = j * 16 + (lane & 15);
#pragma unroll
                        for (int r = 0; r < 4; ++r)
                            ep[(mloc + r) * 132 + sloc] =
                                acc[i][j][r] + bias[m0 + mloc + r];
                    }
                }
            }
            __syncthreads();
#pragma unroll
            for (int cc = 0; cc < 8; ++cc) {
                const int idx = tid + cc * 256;
                const int mloc = idx >> 4, ch = idx & 15;
                float4 a0 = *(const float4*)&ep[mloc * 132 + ch * 8];
                float4 a1 = *(const float4*)&ep[mloc * 132 + ch * 8 + 4];
                float4 r0 = *(const float4*)&rbase[(size_t)mloc * SP + s0 + h * 128 + ch * 8];
                float4 r1 = *(const float4*)&rbase[(size_t)mloc * SP + s0 + h * 128 + ch * 8 + 4];
                bf16x8 pk;
                pk[0] = f2bf(a0.x + r0.x); pk[1] = f2bf(a0.y + r0.y);
                pk[2] = f2bf(a0.z + r0.z); pk[3] = f2bf(a0.w + r0.w);
                pk[4] = f2bf(a1.x + r1.x); pk[5] = f2bf(a1.y + r1.y);
                pk[6] = f2bf(a1.z + r1.z); pk[7] = f2bf(a1.w + r1.w);
                *(bf16x8*)&xo[(size_t)(m0 + mloc) * SP + s0 + h * 128 + ch * 8] = pk;
#pragma unroll
                for (int k = 0; k < 8; ++k) {
                    const double xv = (double)bf2f(pk[k]);
                    ls += xv; lss += xv * xv;
                }
            }
        }
        __shared__ double s1[256], s2[256];
        s1[tid] = ls; s2[tid] = lss;
        __syncthreads();
        for (int st = 128; st > 0; st >>= 1) {
            if (tid < st) { s1[tid] += s1[tid + st]; s2[tid] += s2[tid + st]; }
            __syncthreads();
        }
        if (tid == 0) {
            partials[2 * blockIdx.x] = s1[0];
            partials[2 * blockIdx.x + 1] = s2[0];
        }
    }
}

// ---------------- K softmax stats: online merge of per-block partials ------
__global__ __launch_bounds__(256)
void kstats_reduce_kernel(const float2* __restrict__ kpart, float2* __restrict__ st)
{
    const int row = blockIdx.x * 256 + threadIdx.x;   // 8 x 256 = 2048
    const float2* p = kpart + (size_t)row * SBLKS;
    float m = -1e30f, s = 0.f;
    for (int b = 0; b < SBLKS; ++b) {
        float2 e = p[b];
        float nm = fmaxf(m, e.x);
        s = s * __expf(m - nm) + e.y * __expf(e.x - nm);
        m = nm;
    }
    st[row] = (float2){m, 1.f / s};
}

// ---------------- ctx = softmax(K) . V^T via MFMA --------------------------
__global__ __launch_bounds__(256)
void ctx_mfma_kernel(const short* __restrict__ Kb, const short* __restrict__ Vb,
                     const float2* __restrict__ stats, float* __restrict__ part)
{
    const int chunk = blockIdx.x, nh = blockIdx.y;
    const short* Kp = Kb + (size_t)nh * 64 * SP;
    const short* Vp = Vb + (size_t)nh * 64 * SP;
    __shared__ short lK[64 * 256];
    __shared__ short lV[64 * 256];
    const int tid = threadIdx.x;
    const int w = tid >> 6, lane = tid & 63;
    const int wr = w >> 1, wc = w & 1;
    f32x4 acc[2][2];
#pragma unroll
    for (int i = 0; i < 2; ++i)
#pragma unroll
        for (int j = 0; j < 2; ++j)
            acc[i][j] = (f32x4){0.f, 0.f, 0.f, 0.f};

    float km8[8], ki8[8];
#pragma unroll
    for (int ps = 0; ps < 8; ++ps) {
        float2 s = stats[nh * 64 + (tid >> 5) + ps * 8];
        km8[ps] = s.x; ki8[ps] = s.y;
    }

    for (int sub = 0; sub < 7; ++sub) {
        const int sOff = chunk * 1792 + sub * 256;
#pragma unroll
        for (int cc = 0; cc < 8; ++cc) {
            const int ch = w * 8 + cc;
            const int row = ch * 2 + (lane >> 5);
            const int sc = lane & 31;
            gload16(Vp + (size_t)row * SP + sOff + ((sc ^ (row & 7)) << 3),
                    &lV[ch * 512]);
        }
#pragma unroll
        for (int ps = 0; ps < 8; ++ps) {
            const int row = (tid >> 5) + ps * 8;
            const int sc = tid & 31;
            bf16x8 kv = *(const bf16x8*)(Kp + (size_t)row * SP + sOff + sc * 8);
            bf16x8 ev;
#pragma unroll
            for (int j = 0; j < 8; ++j)
                ev[j] = f2bf(__expf(bf2f(kv[j]) - km8[ps]) * ki8[ps]);
            *(bf16x8*)&lK[row * 256 + ((sc ^ (row & 7)) << 3)] = ev;
        }
        __syncthreads();
#pragma unroll
        for (int ks = 0; ks < 8; ++ks) {
            const int kb = ks * 4 + (lane >> 4);
            bf16x8 ak[2], bv[2];
#pragma unroll
            for (int i = 0; i < 2; ++i) {
                const int rk = wr * 32 + i * 16 + (lane & 15);
                ak[i] = *(const bf16x8*)&lK[rk * 256 + ((kb ^ (rk & 7)) << 3)];
            }
#pragma unroll
            for (int j = 0; j < 2; ++j) {
                const int rv = wc * 32 + j * 16 + (lane & 15);
                bv[j] = *(const bf16x8*)&lV[rv * 256 + ((kb ^ (rv & 7)) << 3)];
            }
#pragma unroll
            for (int i = 0; i < 2; ++i)
#pragma unroll
                for (int j = 0; j < 2; ++j)
                    acc[i][j] = __builtin_amdgcn_mfma_f32_16x16x32_bf16(
                        ak[i], bv[j], acc[i][j], 0, 0, 0);
        }
        __syncthreads();
    }
    float* op = part + ((size_t)nh * CTX_CHUNKS + chunk) * 4096;
#pragma unroll
    for (int i = 0; i < 2; ++i)
#pragma unroll
        for (int j = 0; j < 2; ++j)
#pragma unroll
            for (int r = 0; r < 4; ++r) {
                const int k = wr * 32 + i * 16 + (lane >> 4) * 4 + r;
                const int v = wc * 32 + j * 16 + (lane & 15);
                op[k * 64 + v] = acc[i][j][r];
            }
}

__global__ __launch_bounds__(256)
void ctx_reduce_kernel(const float* __restrict__ part, float* __restrict__ ctx)
{
    const int nh = blockIdx.x;
    for (int e = threadIdx.x; e < 4096; e += 256) {
        float s = 0.f;
        for (int c = 0; c < CTX_CHUNKS; ++c)
            s += part[((size_t)nh * CTX_CHUNKS + c) * 4096 + e];
        ctx[(size_t)nh * 4096 + e] = s;
    }
}

// ---------------- att = ctx^T . softmaxQ via MFMA --------------------------
__global__ __launch_bounds__(256)
void att_kernel(const float* __restrict__ ctx, const short* __restrict__ Qb,
                short* __restrict__ out)
{
    const int nh = blockIdx.y;
    const int n = nh >> 3, h = nh & 7;
    const int s0 = blockIdx.x * 64;
    const float* cp = ctx + (size_t)nh * 4096;
    __shared__ short lC[64 * 64];
    __shared__ short lQ[64 * 64];
    __shared__ float red[64][4];
    __shared__ short lO[64 * 72];
    const int tid = threadIdx.x;
    const int w = tid >> 6, lane = tid & 63;

#pragma unroll
    for (int u = 0; u < 2; ++u) {
        const int si = (tid >> 6) + u * 4;
        const int v = tid & 63;
        bf16x8 pk;
#pragma unroll
        for (int j = 0; j < 8; ++j) pk[j] = f2bf(cp[(si * 8 + j) * 64 + v]);
        *(bf16x8*)&lC[v * 64 + ((si ^ (v & 7)) << 3)] = pk;
    }
    const int sq = tid >> 2, qpart = tid & 3;
    const short* Qrow = Qb + ((size_t)n * SP + s0 + sq) * 512 + h * 64 + qpart * 16;
    bf16x8 q0 = *(const bf16x8*)(Qrow);
    bf16x8 q1 = *(const bf16x8*)(Qrow + 8);
    float e[16];
    float mx = -1e30f;
#pragma unroll
    for (int j = 0; j < 8; ++j) {
        e[j] = bf2f(q0[j]); e[8 + j] = bf2f(q1[j]);
        mx = fmaxf(mx, fmaxf(e[j], e[8 + j]));
    }
    red[sq][qpart] = mx;
    __syncthreads();
    mx = fmaxf(fmaxf(red[sq][0], red[sq][1]), fmaxf(red[sq][2], red[sq][3]));
    float sum = 0.f;
#pragma unroll
    for (int j = 0; j < 16; ++j) { e[j] = __expf(e[j] - mx); sum += e[j]; }
    __syncthreads();
    red[sq][qpart] = sum;
    __syncthreads();
    const float sinv = 1.f / (red[sq][0] + red[sq][1] + red[sq][2] + red[sq][3]);
    bf16x8 p0, p1;
#pragma unroll
    for (int j = 0; j < 8; ++j) {
        p0[j] = f2bf(e[j] * sinv);
        p1[j] = f2bf(e[8 + j] * sinv);
    }
    *(bf16x8*)&lQ[sq * 64 + (((qpart * 2) ^ (sq & 7)) << 3)] = p0;
    *(bf16x8*)&lQ[sq * 64 + (((qpart * 2 + 1) ^ (sq & 7)) << 3)] = p1;
    __syncthreads();

    f32x4 acc[4];
#pragma unroll
    for (int i = 0; i < 4; ++i) acc[i] = (f32x4){0.f, 0.f, 0.f, 0.f};
    const int srow = w * 16 + (lane & 15);
#pragma unroll
    for (int ks = 0; ks < 2; ++ks) {
        const int kb = ks * 4 + (lane >> 4);
        bf16x8 bq = *(const bf16x8*)&lQ[srow * 64 + ((kb ^ (srow & 7)) << 3)];
#pragma unroll
        for (int i = 0; i < 4; ++i) {
            const int vr = i * 16 + (lane & 15);
            bf16x8 av = *(const bf16x8*)&lC[vr * 64 + ((kb ^ (vr & 7)) << 3)];
            acc[i] = __builtin_amdgcn_mfma_f32_16x16x32_bf16(av, bq, acc[i], 0, 0, 0);
        }
    }
#pragma unroll
    for (int i = 0; i < 4; ++i)
#pragma unroll
        for (int r = 0; r < 4; ++r)
            lO[(i * 16 + (lane >> 4) * 4 + r) * 72 + w * 16 + (lane & 15)] =
                f2bf(acc[i][r]);
    __syncthreads();
    short* op = out + (size_t)nh * 64 * SP;
#pragma unroll
    for (int cc = 0; cc < 2; ++cc) {
        const int idx = tid + cc * 256;
        const int v = idx >> 3, ch = idx & 7;
        bf16x8 t = *(const bf16x8*)&lO[v * 72 + ch * 8];
        *(bf16x8*)&op[(size_t)v * SP + s0 + ch * 8] = t;
    }
}

// ---------------- LN finalize ----------------------------------------------
__global__ __launch_bounds__(256)
void stats_final_kernel(const double* __restrict__ partials, float* __restrict__ mv)
{
    double ls = 0.0, lss = 0.0;
    for (int i = threadIdx.x; i < STATS_PARTS; i += 256) {
        ls += partials[2 * i];
        lss += partials[2 * i + 1];
    }
    __shared__ double s1[256], s2[256];
    const int tid = threadIdx.x;
    s1[tid] = ls; s2[tid] = lss;
    __syncthreads();
    for (int s = 128; s > 0; s >>= 1) {
        if (tid < s) { s1[tid] += s1[tid + s]; s2[tid] += s2[tid + s]; }
        __syncthreads();
    }
    if (tid == 0) {
        double mean = s1[0] / TOTAL_ELEMS;
        double var = s2[0] / TOTAL_ELEMS - mean * mean;
        mv[0] = (float)mean;
        mv[1] = (float)(1.0 / sqrt(var + 1e-5));
    }
}

__global__ __launch_bounds__(256)
void normalize_kernel(const short* __restrict__ xb, float* __restrict__ out,
                      const float* __restrict__ mv)
{
    const float mean = mv[0], inv = mv[1];
    size_t i = ((size_t)blockIdx.x * 256 + threadIdx.x) * 8;
    const size_t tot = (size_t)NB;
    const size_t step = (size_t)gridDim.x * 2048;
    for (; i < tot; i += step) {
        bf16x8 v = *(const bf16x8*)&xb[i];
        float4 a, b;
        a.x = (bf2f(v[0]) - mean) * inv; a.y = (bf2f(v[1]) - mean) * inv;
        a.z = (bf2f(v[2]) - mean) * inv; a.w = (bf2f(v[3]) - mean) * inv;
        b.x = (bf2f(v[4]) - mean) * inv; b.y = (bf2f(v[5]) - mean) * inv;
        b.z = (bf2f(v[6]) - mean) * inv; b.w = (bf2f(v[7]) - mean) * inv;
        *(float4*)&out[i] = a;
        *(float4*)&out[i + 4] = b;
    }
}

// ---------------------------------------------------------------------------
extern "C" void kernel_launch(void* const* d_in, const int* in_sizes, int n_in,
                              void* d_out, int out_size, void* d_ws, size_t ws_size,
                              hipStream_t stream)
{
    (void)in_sizes; (void)n_in; (void)out_size; (void)ws_size;
    const float* rgb = (const float*)d_in[0];
    const float* flow = (const float*)d_in[1];
    float* ws = (float*)d_ws;

    short* bufK = (short*)ws;                        // [N,512,S] bf16
    short* bufQ = (short*)(ws + NB / 2);             // [N,S,512] bf16
    short* bufV = (short*)(ws + NB);                 // V/agg [N,512,S] bf16
    short* actK = (short*)(ws + 3 * NB / 2);         // [N,256,S] bf16
    short* actQ = (short*)(ws + 7 * NB / 4);         // [N,256,S] bf16
    short* actV = (short*)(ws + 2 * NB);             // [N,256,S] bf16
    short* wB   = (short*)(ws + 9 * NB / 4);         // 655360 bf16
    float2* rowStats = (float2*)(wB + 655360);       // 2048
    float* ctxBuf = (float*)(rowStats + 2048);       // 32*4096
    double* partials = (double*)(ctxBuf + 32 * 4096);
    float* mv = (float*)(partials + 2 * STATS_PARTS);
    float2* kpart = (float2*)(mv + 8);               // 2048*49 float2
    float* ctxPart = ws + 3 * NB / 2;                // alias act region
    short* rpDw = actK;                              // rp dw out (spans actK+actQ)
    short* xb = bufK;                                // x bf16 (bufK dead after ctx)

    const size_t nsA = (size_t)C2 * SP, csA = SP;    // K/V [n][c][s]

    wcvt_kernel<<<2560, 256, 0, stream>>>(
        (const float*)d_in[4], (const float*)d_in[12], (const float*)d_in[16],
        (const float*)d_in[24], (const float*)d_in[8], (const float*)d_in[20],
        (const float*)d_in[28], wB);

    // ---- projections per stream: dwv, batched K+V pw, Q pw ----
    for (int st = 0; st < 2; ++st) {
        const float* src = st ? flow : rgb;
        const int kI = st ? 14 : 2, qI = st ? 18 : 6, vI = st ? 22 : 10;
        const int choff = st ? 256 : 0;
        dwv_kernel<float, 3><<<dim3(2, C1, NN), 256, 0, stream>>>(
            src,
            (const float*)d_in[kI], (const float*)d_in[kI + 1], actK,
            (const float*)d_in[qI], (const float*)d_in[qI + 1], actQ,
            (const float*)d_in[vI], (const float*)d_in[vI + 1], actV, C1);
        pw_mfma_kernel<0><<<dim3(SBLKS, 4, NN), 256, 0, stream>>>(
            wB + (size_t)(st ? 2 : 0) * 65536, (const float*)d_in[kI + 3], actK, bufK,
            wB + (size_t)(st ? 3 : 1) * 65536, (const float*)d_in[vI + 3], actV, bufV,
            nullptr, nullptr, nullptr, kpart, C1, nsA, csA, choff);
        pw_mfma_kernel<1><<<dim3(SBLKS, 2, NN), 256, 0, stream>>>(
            wB + (size_t)(st ? 5 : 4) * 65536, (const float*)d_in[qI + 3], actQ, bufQ,
            nullptr, nullptr, nullptr, nullptr,
            nullptr, nullptr, nullptr, nullptr, C1, 0, 0, choff);
    }

    // ---- attention ----
    kstats_reduce_kernel<<<8, 256, 0, stream>>>(kpart, rowStats);
    ctx_mfma_kernel<<<dim3(CTX_CHUNKS, NN * HEADS), 256, 0, stream>>>(
        bufK, bufV, rowStats, ctxPart);
    ctx_reduce_kernel<<<NN * HEADS, 256, 0, stream>>>(ctxPart, ctxBuf);
    att_kernel<<<dim3(SP / 64, NN * HEADS), 256, 0, stream>>>(
        ctxBuf, bufQ, bufV);   // bufV becomes aggregated [N,512,S]

    // ---- reprojection: dw(512) -> pw GEMM (x bf16 + LN partials) ----
    dwv_kernel<short, 1><<<dim3(2, C2, NN), 256, 0, stream>>>(
        bufV, (const float*)d_in[26], (const float*)d_in[27], rpDw,
        nullptr, nullptr, nullptr, nullptr, nullptr, nullptr, C2);
    pw_mfma_kernel<2><<<STATS_PARTS, 256, 0, stream>>>(
        wB + 6 * 65536, (const float*)d_in[29], rpDw, xb,
        nullptr, nullptr, nullptr, nullptr,
        rgb, flow, partials, nullptr, C2, 0, 0, 0);

    // ---- LN finalize ----
    stats_final_kernel<<<1, 256, 0, stream>>>(partials, mv);
    normalize_kernel<<<2048, 256, 0, stream>>>(xb, (float*)d_out, mv);
}

// Round 13
// 419.078 us; speedup vs baseline: 1.3647x; 1.3647x over previous
//
#include <hip/hip_runtime.h>
#include <math.h>

// ---------------------------------------------------------------------------
// EfficientAttention (dual-stream) — round 13: REVERT to round-11 config
// (measured 419.6 us; round-12 wide-tile regressed to 572 via occupancy
// collapse). 128x128 pw tile, 1-barrier double-buffered K-loop, reduced
// traffic (bf16 x, fused K-stats, XCD swizzle on rp), MFMA attention.
// ---------------------------------------------------------------------------

constexpr int NN = 4;
constexpr int C1 = 256;
constexpr int C2 = 512;
constexpr int TT = 16;
constexpr int SP = TT * 28 * 28;                  // 12544
constexpr long long NB = (long long)NN * C2 * SP; // 25,690,112
constexpr int HEADS = 8;
constexpr int CTX_CHUNKS = 7;
constexpr int SBLKS = 98;                         // SP / 128
constexpr int STATS_PARTS = SBLKS * 4 * 4;        // rp GEMM grid = 1568
constexpr double TOTAL_ELEMS = (double)NB;

typedef __attribute__((ext_vector_type(8))) short bf16x8;
typedef __attribute__((ext_vector_type(4))) short bf16x4;
typedef __attribute__((ext_vector_type(4))) float f32x4;

__device__ __forceinline__ short f2bf(float f)
{
    unsigned u = __float_as_uint(f);
    unsigned r = u + 0x7FFFu + ((u >> 16) & 1u);
    return (short)(r >> 16);
}
__device__ __forceinline__ float bf2f(short s)
{
    return __uint_as_float(((unsigned)(unsigned short)s) << 16);
}

__device__ __forceinline__ float4 loadvec4(const float* p)
{
    return *(const float4*)p;
}
__device__ __forceinline__ float4 loadvec4(const short* p)
{
    bf16x4 v = *(const bf16x4*)p;
    return (float4){bf2f(v[0]), bf2f(v[1]), bf2f(v[2]), bf2f(v[3])};
}

__device__ __forceinline__ void gload16(const short* g, short* l)
{
    __builtin_amdgcn_global_load_lds(
        (const __attribute__((address_space(1))) unsigned int*)g,
        (__attribute__((address_space(3))) unsigned int*)l,
        16, 0, 0);
}

// ---------------- merged fp32 -> bf16 weight conversion --------------------
__global__ __launch_bounds__(256)
void wcvt_kernel(const float* __restrict__ w0, const float* __restrict__ w1,
                 const float* __restrict__ w2, const float* __restrict__ w3,
                 const float* __restrict__ w4, const float* __restrict__ w5,
                 const float* __restrict__ w6, short* __restrict__ out)
{
    int i = blockIdx.x * 256 + threadIdx.x;
    if (i >= 655360) return;
    const float* src; int off;
    if (i < 393216) {
        int seg = i >> 16; off = i & 65535;
        src = seg == 0 ? w0 : seg == 1 ? w1 : seg == 2 ? w2
            : seg == 3 ? w3 : seg == 4 ? w4 : w5;
    } else { src = w6; off = i - 393216; }
    out[i] = f2bf(src[off]);
}

// ---------------- depthwise 3x3x3 (prefetched, vectorized) -----------------
template<typename IT, int NSET>
__global__ __launch_bounds__(256)
void dwv_kernel(const IT* __restrict__ in,
                const float* __restrict__ w0c, const float* __restrict__ b0c,
                short* __restrict__ o0,
                const float* __restrict__ w1c, const float* __restrict__ b1c,
                short* __restrict__ o1,
                const float* __restrict__ w2c, const float* __restrict__ b2c,
                short* __restrict__ o2, int Cin)
{
    const int split = blockIdx.x, c = blockIdx.y, n = blockIdx.z;
    const int t0 = split * 8, t1 = t0 + 8;
    const int zs = (t0 - 1 > 0) ? t0 - 1 : 0;
    const int ze = (t1 < 15) ? t1 : 15;
    __shared__ float tile[2][900];
    const int tid = threadIdx.x;
    const size_t ibase = ((size_t)(n * Cin + c)) * TT * 784;
    const IT* inp = in + ibase;

    const float* wp[3] = {w0c, w1c, w2c};
    const float* bp[3] = {b0c, b1c, b2c};
    short* op[3] = {o0, o1, o2};
    float w[NSET][27], bv[NSET];
#pragma unroll
    for (int g = 0; g < NSET; ++g) {
#pragma unroll
        for (int i = 0; i < 27; ++i) w[g][i] = wp[g][c * 27 + i];
        bv[g] = bp[g][c];
    }

    for (int i = tid; i < 1800; i += 256) ((float*)tile)[i] = 0.f;

    const bool act = tid < 196;
    const int pos = tid * 4;
    const int hh = pos / 28, ww = pos - hh * 28;
    const int ladr = (hh + 1) * 30 + ww + 1;
    const int rbase = hh * 30 + ww;

    float4 preg = {0.f, 0.f, 0.f, 0.f};
    if (act) preg = loadvec4(inp + (size_t)zs * 784 + pos);

    float a0[NSET][4], a1[NSET][4], a2[NSET][4];
#pragma unroll
    for (int g = 0; g < NSET; ++g)
#pragma unroll
        for (int k = 0; k < 4; ++k) { a0[g][k] = bv[g]; a1[g][k] = bv[g]; a2[g][k] = bv[g]; }

    for (int z = zs; z <= ze; ++z) {
        float* tb = tile[z & 1];
        __syncthreads();
        if (act) {
            tb[ladr] = preg.x; tb[ladr + 1] = preg.y;
            tb[ladr + 2] = preg.z; tb[ladr + 3] = preg.w;
            if (z < ze) preg = loadvec4(inp + (size_t)(z + 1) * 784 + pos);
        }
        __syncthreads();
        if (act) {
            float v[3][6];
#pragma unroll
            for (int r = 0; r < 3; ++r)
#pragma unroll
                for (int j = 0; j < 6; ++j)
                    v[r][j] = tb[rbase + r * 30 + j];
#pragma unroll
            for (int g = 0; g < NSET; ++g)
#pragma unroll
                for (int dh = 0; dh < 3; ++dh)
#pragma unroll
                    for (int dw = 0; dw < 3; ++dw) {
                        const float wa = w[g][18 + dh * 3 + dw];
                        const float wb = w[g][9 + dh * 3 + dw];
                        const float wc2 = w[g][dh * 3 + dw];
#pragma unroll
                        for (int k = 0; k < 4; ++k) {
                            const float val = v[dh][k + dw];
                            a0[g][k] += val * wa;
                            a1[g][k] += val * wb;
                            a2[g][k] += val * wc2;
                        }
                    }
            if (z - 1 >= t0) {
#pragma unroll
                for (int g = 0; g < NSET; ++g) {
                    bf16x4 pk;
#pragma unroll
                    for (int k = 0; k < 4; ++k) pk[k] = f2bf(a0[g][k]);
                    *(bf16x4*)&op[g][ibase + (size_t)(z - 1) * 784 + pos] = pk;
                }
            }
#pragma unroll
            for (int g = 0; g < NSET; ++g)
#pragma unroll
                for (int k = 0; k < 4; ++k) {
                    a0[g][k] = a1[g][k]; a1[g][k] = a2[g][k]; a2[g][k] = bv[g];
                }
        }
    }
    if (act && ze >= t0 && ze < t1) {
#pragma unroll
        for (int g = 0; g < NSET; ++g) {
            bf16x4 pk;
#pragma unroll
            for (int k = 0; k < 4; ++k) pk[k] = f2bf(a0[g][k]);
            *(bf16x4*)&op[g][ibase + (size_t)ze * 784 + pos] = pk;
        }
    }
}

// ---------------- pointwise conv: bf16 MFMA GEMM (2-phase prefetch) --------
// MODE 0: batched K(seg0)+V(seg1) -> bf16 [n][c][s]; K also emits per-block
//         row (max, expsum) partials to kpart[row][sBlk].
// MODE 1: Q -> bf16 [n][s][512].
// MODE 2: rp -> x bf16 [n][c][s] (acc+bias+resid, rounded) + LN partials
//         (on rounded values); grid 1D with XCD-chunked swizzle.
template<int MODE>
__global__ __launch_bounds__(256)
void pw_mfma_kernel(const short* __restrict__ WbA, const float* __restrict__ biasA,
                    const short* __restrict__ actA, short* __restrict__ outA,
                    const short* __restrict__ WbV, const float* __restrict__ biasV,
                    const short* __restrict__ actV, short* __restrict__ outV,
                    const float* __restrict__ rgb, const float* __restrict__ flow,
                    double* __restrict__ partials, float2* __restrict__ kpart,
                    int Cin, size_t nStride, size_t cStride, int chOff)
{
    __shared__ short smem[34816];     // 69632 B: lA 8192x2 | Bs 9216x2
    const int tid = threadIdx.x;
    const int w = tid >> 6, lane = tid & 63;
    int s0, m0, n, seg = 0, sBlk;
    if constexpr (MODE == 2) {
        const int b = blockIdx.x;
        const int r = b & 7, t = b >> 3;
        const int mBlk = t & 3, q = t >> 2;
        const int g = q * 8 + r;                  // bijective: 392 groups
        n = g / SBLKS; sBlk = g % SBLKS;
        s0 = sBlk * 128; m0 = mBlk * 128;
    } else {
        sBlk = blockIdx.x; s0 = sBlk * 128; n = blockIdx.z;
        if constexpr (MODE == 0) { seg = blockIdx.y >> 1; m0 = (blockIdx.y & 1) * 128; }
        else m0 = blockIdx.y * 128;
    }
    const short* Wb = (MODE == 0 && seg) ? WbV : WbA;
    const float* bias = (MODE == 0 && seg) ? biasV : biasA;
    const short* actp = (MODE == 0 && seg) ? actV : actA;
    short* outB = (MODE == 0 && seg) ? outV : outA;

    const short* aSrc = Wb + (size_t)m0 * Cin;
    const short* bSrc = actp + (size_t)n * Cin * SP;
    f32x4 acc[4][4];
#pragma unroll
    for (int i = 0; i < 4; ++i)
#pragma unroll
        for (int j = 0; j < 4; ++j)
            acc[i][j] = (f32x4){0.f, 0.f, 0.f, 0.f};
    const int lrow = lane >> 3, lslot = lane & 7;
    const int wr = w >> 1, wc = w & 1;
    const int kg = tid >> 4, scb = tid & 15;   // B staging: 4 k-rows x 8 s
    const int nt = Cin >> 6;

    // ---- prologue: stage tile 0 into buffer 0 ----
    {
        short* nA = smem;
        short* nB = smem + 16384;
#pragma unroll
        for (int cc = 0; cc < 4; ++cc) {
            const int chunk = w * 4 + cc;
            const int row = chunk * 8 + lrow;
            const int ss = lslot ^ (row & 7);
            gload16(aSrc + (size_t)row * Cin + ss * 8, &nA[chunk * 512]);
        }
        bf16x8 breg[4];
#pragma unroll
        for (int r = 0; r < 4; ++r)
            breg[r] = *(const bf16x8*)(bSrc + (size_t)(kg * 4 + r) * SP + s0 + scb * 8);
#pragma unroll
        for (int j = 0; j < 8; ++j) {
            bf16x4 pk;
#pragma unroll
            for (int r = 0; r < 4; ++r) pk[r] = breg[r][j];
            const int srow = scb * 8 + j;
            const int slot = (kg >> 1) ^ (scb & 7);
            *(bf16x4*)&nB[srow * 72 + slot * 8 + (kg & 1) * 4] = pk;
        }
    }
    __syncthreads();

    for (int t = 0; t < nt; ++t) {
        short* cA = smem + (t & 1) * 8192;
        short* cB = smem + 16384 + (t & 1) * 9216;
        short* nA = smem + ((t + 1) & 1) * 8192;
        short* nB = smem + 16384 + ((t + 1) & 1) * 9216;
        const bool more = (t + 1) < nt;
        bf16x8 bnext[4];
        if (more) {
            const int kt = (t + 1) << 6;
#pragma unroll
            for (int cc = 0; cc < 4; ++cc) {
                const int chunk = w * 4 + cc;
                const int row = chunk * 8 + lrow;
                const int ss = lslot ^ (row & 7);
                gload16(aSrc + (size_t)row * Cin + kt + ss * 8, &nA[chunk * 512]);
            }
#pragma unroll
            for (int r = 0; r < 4; ++r)
                bnext[r] = *(const bf16x8*)(bSrc + (size_t)(kt + kg * 4 + r) * SP + s0 + scb * 8);
        }
#pragma unroll
        for (int kf = 0; kf < 2; ++kf) {
            bf16x8 af[4], bfr[4];
            const int kb = kf * 4 + (lane >> 4);
#pragma unroll
            for (int i = 0; i < 4; ++i) {
                const int row = wr * 64 + i * 16 + (lane & 15);
                af[i] = *(const bf16x8*)&cA[row * 64 + ((kb ^ (row & 7)) << 3)];
            }
#pragma unroll
            for (int j = 0; j < 4; ++j) {
                const int srow = wc * 64 + j * 16 + (lane & 15);
                bfr[j] = *(const bf16x8*)&cB[srow * 72 + ((kb ^ ((srow >> 3) & 7)) << 3)];
            }
#pragma unroll
            for (int i = 0; i < 4; ++i)
#pragma unroll
                for (int j = 0; j < 4; ++j)
                    acc[i][j] = __builtin_amdgcn_mfma_f32_16x16x32_bf16(
                        af[i], bfr[j], acc[i][j], 0, 0, 0);
        }
        if (more) {
#pragma unroll
            for (int j = 0; j < 8; ++j) {
                bf16x4 pk;
#pragma unroll
                for (int r = 0; r < 4; ++r) pk[r] = bnext[r][j];
                const int srow = scb * 8 + j;
                const int slot = (kg >> 1) ^ (scb & 7);
                *(bf16x4*)&nB[srow * 72 + slot * 8 + (kg & 1) * 4] = pk;
            }
        }
        __syncthreads();
    }

    if constexpr (MODE == 0) {
        short* ep = smem;                      // [128][136] bf16
#pragma unroll
        for (int i = 0; i < 4; ++i) {
            const int mloc = wr * 64 + i * 16 + (lane >> 4) * 4;
#pragma unroll
            for (int j = 0; j < 4; ++j) {
                const int sloc = wc * 64 + j * 16 + (lane & 15);
#pragma unroll
                for (int r = 0; r < 4; ++r)
                    ep[(mloc + r) * 136 + sloc] =
                        f2bf(acc[i][j][r] + bias[m0 + mloc + r]);
            }
        }
        __syncthreads();
        short* op = outB + (size_t)n * nStride;
#pragma unroll
        for (int cc = 0; cc < 8; ++cc) {
            const int idx = tid + cc * 256;
            const int mloc = idx >> 4, ch = idx & 15;
            bf16x8 v = *(const bf16x8*)&ep[mloc * 136 + ch * 8];
            *(bf16x8*)&op[(size_t)(chOff + m0 + mloc) * cStride + s0 + ch * 8] = v;
        }
        if (seg == 0) {
            // per-row softmax partials over this block's 128 s
            const int row = tid >> 1, half = tid & 1;
            const short* rp = &ep[row * 136 + half * 64];
            float mx = -1e30f;
#pragma unroll 8
            for (int j = 0; j < 64; ++j) mx = fmaxf(mx, bf2f(rp[j]));
            float sum = 0.f;
#pragma unroll 8
            for (int j = 0; j < 64; ++j) sum += __expf(bf2f(rp[j]) - mx);
            const float mo = __shfl_xor(mx, 1, 64);
            const float so = __shfl_xor(sum, 1, 64);
            const float mg = fmaxf(mx, mo);
            const float sg = sum * __expf(mx - mg) + so * __expf(mo - mg);
            if (half == 0)
                kpart[(size_t)(n * 512 + chOff + m0 + row) * SBLKS + sBlk] =
                    (float2){mg, sg};
        }
    } else if constexpr (MODE == 1) {
        short* ep = smem;                      // [128 s][136 m]
#pragma unroll
        for (int i = 0; i < 4; ++i) {
            const int mb = wr * 64 + i * 16 + (lane >> 4) * 4;
#pragma unroll
            for (int j = 0; j < 4; ++j) {
                const int sloc = wc * 64 + j * 16 + (lane & 15);
                bf16x4 pk;
#pragma unroll
                for (int r = 0; r < 4; ++r)
                    pk[r] = f2bf(acc[i][j][r] + bias[m0 + mb + r]);
                *(bf16x4*)&ep[sloc * 136 + mb] = pk;
            }
        }
        __syncthreads();
#pragma unroll
        for (int cc = 0; cc < 8; ++cc) {
            const int idx = tid + cc * 256;
            const int sloc = idx >> 4, ch = idx & 15;
            bf16x8 v = *(const bf16x8*)&ep[sloc * 136 + ch * 8];
            *(bf16x8*)&outA[((size_t)n * SP + s0 + sloc) * 512 + chOff + m0 + ch * 8] = v;
        }
    } else {
        float* ep = (float*)smem;              // [128][132] f32 (67.6 KB)
#pragma unroll
        for (int i = 0; i < 4; ++i) {
            const int mloc = wr * 64 + i * 16 + (lane >> 4) * 4;
#pragma unroll
            for (int j = 0; j < 4; ++j) {
                const int sloc = wc * 64 + j * 16 + (lane & 15);
#pragma unroll
                for (int r = 0; r < 4; ++r)
                    ep[(mloc + r) * 132 + sloc] =
                        acc[i][j][r] + bias[m0 + mloc + r];
            }
        }
        __syncthreads();
        short* xo = outA + (size_t)n * C2 * SP;
        const float* rbase = (m0 < 256)
            ? rgb + ((size_t)n * 256 + m0) * SP
            : flow + ((size_t)n * 256 + (m0 - 256)) * SP;
        double ls = 0.0, lss = 0.0;
#pragma unroll
        for (int cc = 0; cc < 8; ++cc) {
            const int idx = tid + cc * 256;
            const int mloc = idx >> 4, ch = idx & 15;
            float4 a0 = *(const float4*)&ep[mloc * 132 + ch * 8];
            float4 a1 = *(const float4*)&ep[mloc * 132 + ch * 8 + 4];
            float4 r0 = *(const float4*)&rbase[(size_t)mloc * SP + s0 + ch * 8];
            float4 r1 = *(const float4*)&rbase[(size_t)mloc * SP + s0 + ch * 8 + 4];
            bf16x8 pk;
            pk[0] = f2bf(a0.x + r0.x); pk[1] = f2bf(a0.y + r0.y);
            pk[2] = f2bf(a0.z + r0.z); pk[3] = f2bf(a0.w + r0.w);
            pk[4] = f2bf(a1.x + r1.x); pk[5] = f2bf(a1.y + r1.y);
            pk[6] = f2bf(a1.z + r1.z); pk[7] = f2bf(a1.w + r1.w);
            *(bf16x8*)&xo[(size_t)(m0 + mloc) * SP + s0 + ch * 8] = pk;
#pragma unroll
            for (int k = 0; k < 8; ++k) {
                const double xv = (double)bf2f(pk[k]);
                ls += xv; lss += xv * xv;
            }
        }
        __shared__ double s1[256], s2[256];
        s1[tid] = ls; s2[tid] = lss;
        __syncthreads();
        for (int st = 128; st > 0; st >>= 1) {
            if (tid < st) { s1[tid] += s1[tid + st]; s2[tid] += s2[tid + st]; }
            __syncthreads();
        }
        if (tid == 0) {
            partials[2 * blockIdx.x] = s1[0];
            partials[2 * blockIdx.x + 1] = s2[0];
        }
    }
}

// ---------------- K softmax stats: online merge of per-block partials ------
__global__ __launch_bounds__(256)
void kstats_reduce_kernel(const float2* __restrict__ kpart, float2* __restrict__ st)
{
    const int row = blockIdx.x * 256 + threadIdx.x;   // 8 blocks x 256 = 2048
    const float2* p = kpart + (size_t)row * SBLKS;
    float m = -1e30f, s = 0.f;
    for (int b = 0; b < SBLKS; ++b) {
        float2 e = p[b];
        float nm = fmaxf(m, e.x);
        s = s * __expf(m - nm) + e.y * __expf(e.x - nm);
        m = nm;
    }
    st[row] = (float2){m, 1.f / s};
}

// ---------------- ctx = softmax(K) . V^T via MFMA --------------------------
__global__ __launch_bounds__(256)
void ctx_mfma_kernel(const short* __restrict__ Kb, const short* __restrict__ Vb,
                     const float2* __restrict__ stats, float* __restrict__ part)
{
    const int chunk = blockIdx.x, nh = blockIdx.y;
    const short* Kp = Kb + (size_t)nh * 64 * SP;
    const short* Vp = Vb + (size_t)nh * 64 * SP;
    __shared__ short lK[64 * 256];
    __shared__ short lV[64 * 256];
    const int tid = threadIdx.x;
    const int w = tid >> 6, lane = tid & 63;
    const int wr = w >> 1, wc = w & 1;
    f32x4 acc[2][2];
#pragma unroll
    for (int i = 0; i < 2; ++i)
#pragma unroll
        for (int j = 0; j < 2; ++j)
            acc[i][j] = (f32x4){0.f, 0.f, 0.f, 0.f};

    float km8[8], ki8[8];
#pragma unroll
    for (int ps = 0; ps < 8; ++ps) {
        float2 s = stats[nh * 64 + (tid >> 5) + ps * 8];
        km8[ps] = s.x; ki8[ps] = s.y;
    }

    for (int sub = 0; sub < 7; ++sub) {
        const int sOff = chunk * 1792 + sub * 256;
#pragma unroll
        for (int cc = 0; cc < 8; ++cc) {
            const int ch = w * 8 + cc;
            const int row = ch * 2 + (lane >> 5);
            const int sc = lane & 31;
            gload16(Vp + (size_t)row * SP + sOff + ((sc ^ (row & 7)) << 3),
                    &lV[ch * 512]);
        }
#pragma unroll
        for (int ps = 0; ps < 8; ++ps) {
            const int row = (tid >> 5) + ps * 8;
            const int sc = tid & 31;
            bf16x8 kv = *(const bf16x8*)(Kp + (size_t)row * SP + sOff + sc * 8);
            bf16x8 ev;
#pragma unroll
            for (int j = 0; j < 8; ++j)
                ev[j] = f2bf(__expf(bf2f(kv[j]) - km8[ps]) * ki8[ps]);
            *(bf16x8*)&lK[row * 256 + ((sc ^ (row & 7)) << 3)] = ev;
        }
        __syncthreads();
#pragma unroll
        for (int ks = 0; ks < 8; ++ks) {
            const int kb = ks * 4 + (lane >> 4);
            bf16x8 ak[2], bv[2];
#pragma unroll
            for (int i = 0; i < 2; ++i) {
                const int rk = wr * 32 + i * 16 + (lane & 15);
                ak[i] = *(const bf16x8*)&lK[rk * 256 + ((kb ^ (rk & 7)) << 3)];
            }
#pragma unroll
            for (int j = 0; j < 2; ++j) {
                const int rv = wc * 32 + j * 16 + (lane & 15);
                bv[j] = *(const bf16x8*)&lV[rv * 256 + ((kb ^ (rv & 7)) << 3)];
            }
#pragma unroll
            for (int i = 0; i < 2; ++i)
#pragma unroll
                for (int j = 0; j < 2; ++j)
                    acc[i][j] = __builtin_amdgcn_mfma_f32_16x16x32_bf16(
                        ak[i], bv[j], acc[i][j], 0, 0, 0);
        }
        __syncthreads();
    }
    float* op = part + ((size_t)nh * CTX_CHUNKS + chunk) * 4096;
#pragma unroll
    for (int i = 0; i < 2; ++i)
#pragma unroll
        for (int j = 0; j < 2; ++j)
#pragma unroll
            for (int r = 0; r < 4; ++r) {
                const int k = wr * 32 + i * 16 + (lane >> 4) * 4 + r;
                const int v = wc * 32 + j * 16 + (lane & 15);
                op[k * 64 + v] = acc[i][j][r];
            }
}

__global__ __launch_bounds__(256)
void ctx_reduce_kernel(const float* __restrict__ part, float* __restrict__ ctx)
{
    const int nh = blockIdx.x;
    for (int e = threadIdx.x; e < 4096; e += 256) {
        float s = 0.f;
        for (int c = 0; c < CTX_CHUNKS; ++c)
            s += part[((size_t)nh * CTX_CHUNKS + c) * 4096 + e];
        ctx[(size_t)nh * 4096 + e] = s;
    }
}

// ---------------- att = ctx^T . softmaxQ via MFMA --------------------------
__global__ __launch_bounds__(256)
void att_kernel(const float* __restrict__ ctx, const short* __restrict__ Qb,
                short* __restrict__ out)
{
    const int nh = blockIdx.y;
    const int n = nh >> 3, h = nh & 7;
    const int s0 = blockIdx.x * 64;
    const float* cp = ctx + (size_t)nh * 4096;
    __shared__ short lC[64 * 64];
    __shared__ short lQ[64 * 64];
    __shared__ float red[64][4];
    __shared__ short lO[64 * 72];
    const int tid = threadIdx.x;
    const int w = tid >> 6, lane = tid & 63;

#pragma unroll
    for (int u = 0; u < 2; ++u) {
        const int si = (tid >> 6) + u * 4;
        const int v = tid & 63;
        bf16x8 pk;
#pragma unroll
        for (int j = 0; j < 8; ++j) pk[j] = f2bf(cp[(si * 8 + j) * 64 + v]);
        *(bf16x8*)&lC[v * 64 + ((si ^ (v & 7)) << 3)] = pk;
    }
    const int sq = tid >> 2, qpart = tid & 3;
    const short* Qrow = Qb + ((size_t)n * SP + s0 + sq) * 512 + h * 64 + qpart * 16;
    bf16x8 q0 = *(const bf16x8*)(Qrow);
    bf16x8 q1 = *(const bf16x8*)(Qrow + 8);
    float e[16];
    float mx = -1e30f;
#pragma unroll
    for (int j = 0; j < 8; ++j) {
        e[j] = bf2f(q0[j]); e[8 + j] = bf2f(q1[j]);
        mx = fmaxf(mx, fmaxf(e[j], e[8 + j]));
    }
    red[sq][qpart] = mx;
    __syncthreads();
    mx = fmaxf(fmaxf(red[sq][0], red[sq][1]), fmaxf(red[sq][2], red[sq][3]));
    float sum = 0.f;
#pragma unroll
    for (int j = 0; j < 16; ++j) { e[j] = __expf(e[j] - mx); sum += e[j]; }
    __syncthreads();
    red[sq][qpart] = sum;
    __syncthreads();
    const float sinv = 1.f / (red[sq][0] + red[sq][1] + red[sq][2] + red[sq][3]);
    bf16x8 p0, p1;
#pragma unroll
    for (int j = 0; j < 8; ++j) {
        p0[j] = f2bf(e[j] * sinv);
        p1[j] = f2bf(e[8 + j] * sinv);
    }
    *(bf16x8*)&lQ[sq * 64 + (((qpart * 2) ^ (sq & 7)) << 3)] = p0;
    *(bf16x8*)&lQ[sq * 64 + (((qpart * 2 + 1) ^ (sq & 7)) << 3)] = p1;
    __syncthreads();

    f32x4 acc[4];
#pragma unroll
    for (int i = 0; i < 4; ++i) acc[i] = (f32x4){0.f, 0.f, 0.f, 0.f};
    const int srow = w * 16 + (lane & 15);
#pragma unroll
    for (int ks = 0; ks < 2; ++ks) {
        const int kb = ks * 4 + (lane >> 4);
        bf16x8 bq = *(const bf16x8*)&lQ[srow * 64 + ((kb ^ (srow & 7)) << 3)];
#pragma unroll
        for (int i = 0; i < 4; ++i) {
            const int vr = i * 16 + (lane & 15);
            bf16x8 av = *(const bf16x8*)&lC[vr * 64 + ((kb ^ (vr & 7)) << 3)];
            acc[i] = __builtin_amdgcn_mfma_f32_16x16x32_bf16(av, bq, acc[i], 0, 0, 0);
        }
    }
#pragma unroll
    for (int i = 0; i < 4; ++i)
#pragma unroll
        for (int r = 0; r < 4; ++r)
            lO[(i * 16 + (lane >> 4) * 4 + r) * 72 + w * 16 + (lane & 15)] =
                f2bf(acc[i][r]);
    __syncthreads();
    short* op = out + (size_t)nh * 64 * SP;
#pragma unroll
    for (int cc = 0; cc < 2; ++cc) {
        const int idx = tid + cc * 256;
        const int v = idx >> 3, ch = idx & 7;
        bf16x8 t = *(const bf16x8*)&lO[v * 72 + ch * 8];
        *(bf16x8*)&op[(size_t)v * SP + s0 + ch * 8] = t;
    }
}

// ---------------- LN finalize ----------------------------------------------
__global__ __launch_bounds__(256)
void stats_final_kernel(const double* __restrict__ partials, float* __restrict__ mv)
{
    double ls = 0.0, lss = 0.0;
    for (int i = threadIdx.x; i < STATS_PARTS; i += 256) {
        ls += partials[2 * i];
        lss += partials[2 * i + 1];
    }
    __shared__ double s1[256], s2[256];
    const int tid = threadIdx.x;
    s1[tid] = ls; s2[tid] = lss;
    __syncthreads();
    for (int s = 128; s > 0; s >>= 1) {
        if (tid < s) { s1[tid] += s1[tid + s]; s2[tid] += s2[tid + s]; }
        __syncthreads();
    }
    if (tid == 0) {
        double mean = s1[0] / TOTAL_ELEMS;
        double var = s2[0] / TOTAL_ELEMS - mean * mean;
        mv[0] = (float)mean;
        mv[1] = (float)(1.0 / sqrt(var + 1e-5));
    }
}

__global__ __launch_bounds__(256)
void normalize_kernel(const short* __restrict__ xb, float* __restrict__ out,
                      const float* __restrict__ mv)
{
    const float mean = mv[0], inv = mv[1];
    size_t i = ((size_t)blockIdx.x * 256 + threadIdx.x) * 8;
    const size_t tot = (size_t)NB;
    const size_t step = (size_t)gridDim.x * 2048;
    for (; i < tot; i += step) {
        bf16x8 v = *(const bf16x8*)&xb[i];
        float4 a, b;
        a.x = (bf2f(v[0]) - mean) * inv; a.y = (bf2f(v[1]) - mean) * inv;
        a.z = (bf2f(v[2]) - mean) * inv; a.w = (bf2f(v[3]) - mean) * inv;
        b.x = (bf2f(v[4]) - mean) * inv; b.y = (bf2f(v[5]) - mean) * inv;
        b.z = (bf2f(v[6]) - mean) * inv; b.w = (bf2f(v[7]) - mean) * inv;
        *(float4*)&out[i] = a;
        *(float4*)&out[i + 4] = b;
    }
}

// ---------------------------------------------------------------------------
extern "C" void kernel_launch(void* const* d_in, const int* in_sizes, int n_in,
                              void* d_out, int out_size, void* d_ws, size_t ws_size,
                              hipStream_t stream)
{
    (void)in_sizes; (void)n_in; (void)out_size; (void)ws_size;
    const float* rgb = (const float*)d_in[0];
    const float* flow = (const float*)d_in[1];
    float* ws = (float*)d_ws;

    short* bufK = (short*)ws;                        // [N,512,S] bf16
    short* bufQ = (short*)(ws + NB / 2);             // [N,S,512] bf16
    short* bufV = (short*)(ws + NB);                 // V/agg [N,512,S] bf16
    short* actK = (short*)(ws + 3 * NB / 2);         // [N,256,S] bf16
    short* actQ = (short*)(ws + 7 * NB / 4);         // [N,256,S] bf16
    short* actV = (short*)(ws + 2 * NB);             // [N,256,S] bf16
    short* wB   = (short*)(ws + 9 * NB / 4);         // 655360 bf16
    float2* rowStats = (float2*)(wB + 655360);       // 2048
    float* ctxBuf = (float*)(rowStats + 2048);       // 32*4096
    double* partials = (double*)(ctxBuf + 32 * 4096);
    float* mv = (float*)(partials + 2 * STATS_PARTS);
    float2* kpart = (float2*)(mv + 8);               // 2048*98 float2
    float* ctxPart = ws + 3 * NB / 2;                // alias act region
    short* rpDw = actK;                              // rp dw out (spans actK+actQ)
    short* xb = bufK;                                // x bf16 (bufK dead after ctx)

    const size_t nsA = (size_t)C2 * SP, csA = SP;    // K/V [n][c][s]

    wcvt_kernel<<<2560, 256, 0, stream>>>(
        (const float*)d_in[4], (const float*)d_in[12], (const float*)d_in[16],
        (const float*)d_in[24], (const float*)d_in[8], (const float*)d_in[20],
        (const float*)d_in[28], wB);

    // ---- projections per stream: dwv, batched K+V pw, Q pw ----
    for (int st = 0; st < 2; ++st) {
        const float* src = st ? flow : rgb;
        const int kI = st ? 14 : 2, qI = st ? 18 : 6, vI = st ? 22 : 10;
        const int choff = st ? 256 : 0;
        dwv_kernel<float, 3><<<dim3(2, C1, NN), 256, 0, stream>>>(
            src,
            (const float*)d_in[kI], (const float*)d_in[kI + 1], actK,
            (const float*)d_in[qI], (const float*)d_in[qI + 1], actQ,
            (const float*)d_in[vI], (const float*)d_in[vI + 1], actV, C1);
        pw_mfma_kernel<0><<<dim3(SBLKS, 4, NN), 256, 0, stream>>>(
            wB + (size_t)(st ? 2 : 0) * 65536, (const float*)d_in[kI + 3], actK, bufK,
            wB + (size_t)(st ? 3 : 1) * 65536, (const float*)d_in[vI + 3], actV, bufV,
            nullptr, nullptr, nullptr, kpart, C1, nsA, csA, choff);
        pw_mfma_kernel<1><<<dim3(SBLKS, 2, NN), 256, 0, stream>>>(
            wB + (size_t)(st ? 5 : 4) * 65536, (const float*)d_in[qI + 3], actQ, bufQ,
            nullptr, nullptr, nullptr, nullptr,
            nullptr, nullptr, nullptr, nullptr, C1, 0, 0, choff);
    }

    // ---- attention ----
    kstats_reduce_kernel<<<8, 256, 0, stream>>>(kpart, rowStats);
    ctx_mfma_kernel<<<dim3(CTX_CHUNKS, NN * HEADS), 256, 0, stream>>>(
        bufK, bufV, rowStats, ctxPart);
    ctx_reduce_kernel<<<NN * HEADS, 256, 0, stream>>>(ctxPart, ctxBuf);
    att_kernel<<<dim3(SP / 64, NN * HEADS), 256, 0, stream>>>(
        ctxBuf, bufQ, bufV);   // bufV becomes aggregated [N,512,S]

    // ---- reprojection: dw(512) -> pw GEMM (x bf16 + LN partials) ----
    dwv_kernel<short, 1><<<dim3(2, C2, NN), 256, 0, stream>>>(
        bufV, (const float*)d_in[26], (const float*)d_in[27], rpDw,
        nullptr, nullptr, nullptr, nullptr, nullptr, nullptr, C2);
    pw_mfma_kernel<2><<<STATS_PARTS, 256, 0, stream>>>(
        wB + 6 * 65536, (const float*)d_in[29], rpDw, xb,
        nullptr, nullptr, nullptr, nullptr,
        rgb, flow, partials, nullptr, C2, 0, 0, 0);

    // ---- LN finalize ----
    stats_final_kernel<<<1, 256, 0, stream>>>(partials, mv);
    normalize_kernel<<<2048, 256, 0, stream>>>(xb, (float*)d_out, mv);
}